// Round 6
// baseline (188.810 us; speedup 1.0000x reference)
//
#include <hip/hip_runtime.h>

// Problem constants (hard-coded from reference: SHAPES fixed at trace time)
// Level l: W=48>>l, Hgrid=128>>l, start = 8192 - (8192 >> (2*l)); LEN=8160.

#define LEN 8160
#define NCONV8 (2 * LEN * 256 / 8)   // 522,240  (8-elem conv units)
#define NPACK8 (1280 * 256 / 8)      // 40,960   (8-elem pack units)
#define QPB 4                        // queries per sample block (persistent)

typedef __attribute__((ext_vector_type(8))) short bf16x8;
typedef __attribute__((ext_vector_type(8))) unsigned short u16x8;
typedef __attribute__((ext_vector_type(4))) float f32x4;

// Round-to-nearest-even fp32 -> bf16 (single)
__device__ __forceinline__ unsigned short rne_bf16(float v)
{
    unsigned u = __float_as_uint(v);
    return (unsigned short)((u + 0x7FFFu + ((u >> 16) & 1u)) >> 16);
}

// Round-to-nearest-even split of fp32 into hi+lo bf16 (bf16x3 GEMM trick).
__device__ __forceinline__ void split_bf16(float v, unsigned short* hi, unsigned short* lo)
{
    unsigned u = __float_as_uint(v);
    unsigned r = (u + 0x7FFFu + ((u >> 16) & 1u)) & 0xFFFF0000u;
    float hif = __uint_as_float(r);
    float lof = v - hif;
    unsigned ul = __float_as_uint(lof);
    unsigned rl = (ul + 0x7FFFu + ((ul >> 16) & 1u)) >> 16;
    *hi = (unsigned short)(r >> 16);
    *lo = (unsigned short)rl;
}

__device__ __forceinline__ float bf2f(unsigned short s)
{
    return __uint_as_float(((unsigned)s) << 16);
}

// ---------------------------------------------------------------------------
// prep: convA (split inpf+query into hi/lo planes, 8 elems/thread) + pack
// (weights transposed into hi/lo planes, 8 k's/thread) + concat bias.
// W row space: [0,256)=WvT [256,1024)=BcatT(Ws|Wa|Wts|Wta) [1024,1280)=WoT.
// ---------------------------------------------------------------------------
__global__ __launch_bounds__(256) void prep_kernel(
    const float* __restrict__ inpf, const float* __restrict__ query,
    const float* __restrict__ Ws, const float* __restrict__ bs,
    const float* __restrict__ Wa, const float* __restrict__ ba,
    const float* __restrict__ Wts, const float* __restrict__ bts,
    const float* __restrict__ Wta, const float* __restrict__ bta,
    const float* __restrict__ Wv, const float* __restrict__ Wo,
    unsigned short* __restrict__ Ahi, unsigned short* __restrict__ Alo,
    unsigned short* __restrict__ Qhi, unsigned short* __restrict__ Qlo,
    unsigned short* __restrict__ Whi, unsigned short* __restrict__ Wlo,
    float* __restrict__ bcat)
{
    int idx = blockIdx.x * 256 + threadIdx.x;
    if (idx < NCONV8) {
        int which = (idx >= NCONV8 / 2) ? 1 : 0;
        int off = (idx - which * (NCONV8 / 2)) * 8;
        const float* src = which ? query : inpf;
        float4 a = *(const float4*)(src + off);
        float4 b = *(const float4*)(src + off + 4);
        unsigned short h[8], l[8];
        split_bf16(a.x, &h[0], &l[0]); split_bf16(a.y, &h[1], &l[1]);
        split_bf16(a.z, &h[2], &l[2]); split_bf16(a.w, &h[3], &l[3]);
        split_bf16(b.x, &h[4], &l[4]); split_bf16(b.y, &h[5], &l[5]);
        split_bf16(b.z, &h[6], &l[6]); split_bf16(b.w, &h[7], &l[7]);
        uint4 hv, lv;
        hv.x = h[0] | ((unsigned)h[1] << 16); hv.y = h[2] | ((unsigned)h[3] << 16);
        hv.z = h[4] | ((unsigned)h[5] << 16); hv.w = h[6] | ((unsigned)h[7] << 16);
        lv.x = l[0] | ((unsigned)l[1] << 16); lv.y = l[2] | ((unsigned)l[3] << 16);
        lv.z = l[4] | ((unsigned)l[5] << 16); lv.w = l[6] | ((unsigned)l[7] << 16);
        if (which) { *(uint4*)(Qhi + off) = hv; *(uint4*)(Qlo + off) = lv; }
        else       { *(uint4*)(Ahi + off) = hv; *(uint4*)(Alo + off) = lv; }
    } else if (idx < NCONV8 + NPACK8) {
        int j8 = idx - NCONV8;
        int n = j8 >> 5;
        int k0 = (j8 & 31) << 3;
        unsigned short h[8], l[8];
        #pragma unroll
        for (int t = 0; t < 8; t++) {
            int k = k0 + t;
            float v;
            if (n < 256) v = Wv[k * 256 + n];
            else if (n < 1024) {
                int j = n - 256;
                if (j < 256)      v = Ws [k * 256 + j];
                else if (j < 384) v = Wa [k * 128 + (j - 256)];
                else if (j < 640) v = Wts[k * 256 + (j - 384)];
                else              v = Wta[k * 128 + (j - 640)];
            } else v = Wo[k * 256 + (n - 1024)];
            split_bf16(v, &h[t], &l[t]);
        }
        uint4 hv, lv;
        hv.x = h[0] | ((unsigned)h[1] << 16); hv.y = h[2] | ((unsigned)h[3] << 16);
        hv.z = h[4] | ((unsigned)h[5] << 16); hv.w = h[6] | ((unsigned)h[7] << 16);
        lv.x = l[0] | ((unsigned)l[1] << 16); lv.y = l[2] | ((unsigned)l[3] << 16);
        lv.z = l[4] | ((unsigned)l[5] << 16); lv.w = l[6] | ((unsigned)l[7] << 16);
        *(uint4*)(Whi + n * 256 + k0) = hv;
        *(uint4*)(Wlo + n * 256 + k0) = lv;
    } else if (idx < NCONV8 + NPACK8 + 768) {
        int j = idx - (NCONV8 + NPACK8);
        float v;
        if (j < 256)      v = bs[j];
        else if (j < 384) v = ba[j - 256];
        else if (j < 640) v = bts[j - 384];
        else              v = bta[j - 640];
        bcat[j] = v;
    }
}

// ---------------------------------------------------------------------------
// bf16x3 MFMA GEMM, dual problem-set. Tile 256(M)x64(N), K=256 FULLY resident
// in LDS in fragment order (conflict-free 16B/lane reads), ONE barrier.
// 512 threads = 8 waves; wave owns 32 rows (2 x 16-row subtiles).
// mode: 0 = f32 store, 1 = bf16 (RNE) store.
// ---------------------------------------------------------------------------
__global__ __launch_bounds__(512) void gemm_mfma_dual(
    const unsigned short* __restrict__ A0hi, const unsigned short* __restrict__ A0lo,
    const unsigned short* __restrict__ B0hi, const unsigned short* __restrict__ B0lo,
    const float* __restrict__ bias0, void* __restrict__ C0, int N0, int mode0, int nbx0,
    const unsigned short* __restrict__ A1hi, const unsigned short* __restrict__ A1lo,
    const unsigned short* __restrict__ B1hi, const unsigned short* __restrict__ B1lo,
    const float* __restrict__ bias1, void* __restrict__ C1, int N1, int mode1)
{
    // frag-order LDS: [plane][kt][nt][lane][8 bf16] = 64 KB
    __shared__ unsigned short Bf[2 * 8 * 4 * 64 * 8];
    const int tid = threadIdx.x;
    const int wave = tid >> 6, lane = tid & 63;
    int bx = blockIdx.x;
    const int by = blockIdx.y;

    const unsigned short *Ahi, *Alo, *Bhi, *Blo;
    const float* bias; void* C; int N, mode;
    if (bx < nbx0) {
        Ahi = A0hi; Alo = A0lo; Bhi = B0hi; Blo = B0lo;
        bias = bias0; C = C0; N = N0; mode = mode0;
    } else {
        bx -= nbx0;
        Ahi = A1hi; Alo = A1lo; Bhi = B1hi; Blo = B1lo;
        bias = bias1; C = C1; N = N1; mode = mode1;
    }

    // ---- stage full B tile (both planes) into frag-order LDS ----
    #pragma unroll
    for (int t = 0; t < 8; t++) {
        int f = t * 512 + tid;
        int ln = f & 63, nt = (f >> 6) & 3, kt = (f >> 8) & 7, pl = f >> 11;
        const unsigned short* src = (pl ? Blo : Bhi)
            + (size_t)(bx * 64 + nt * 16 + (ln & 15)) * 256 + kt * 32 + (ln >> 4) * 8;
        *(uint4*)(&Bf[(size_t)f * 8]) = *(const uint4*)src;
    }
    __syncthreads();

    const int lm = lane & 15;     // m within 16-tile / C column
    const int kq = lane >> 4;     // k-quad (0..3)
    const int m0 = by * 256 + wave * 32 + lm;
    const unsigned short* aH0 = Ahi + (size_t)m0 * 256 + kq * 8;
    const unsigned short* aL0 = Alo + (size_t)m0 * 256 + kq * 8;

    f32x4 acc[2][4] = {};
    #pragma unroll
    for (int kt = 0; kt < 8; kt++) {
        bf16x8 ah0 = *(const bf16x8*)(aH0 + kt * 32);
        bf16x8 al0 = *(const bf16x8*)(aL0 + kt * 32);
        bf16x8 ah1 = *(const bf16x8*)(aH0 + 16 * 256 + kt * 32);
        bf16x8 al1 = *(const bf16x8*)(aL0 + 16 * 256 + kt * 32);
        #pragma unroll
        for (int nt = 0; nt < 4; nt++) {
            const int fb = (kt * 4 + nt) * 64 + lane;
            bf16x8 bh = *(const bf16x8*)(&Bf[(size_t)fb * 8]);
            bf16x8 bl = *(const bf16x8*)(&Bf[(size_t)(fb + 2048) * 8]);
            acc[0][nt] = __builtin_amdgcn_mfma_f32_16x16x32_bf16(ah0, bh, acc[0][nt], 0, 0, 0);
            acc[0][nt] = __builtin_amdgcn_mfma_f32_16x16x32_bf16(ah0, bl, acc[0][nt], 0, 0, 0);
            acc[0][nt] = __builtin_amdgcn_mfma_f32_16x16x32_bf16(al0, bh, acc[0][nt], 0, 0, 0);
            acc[1][nt] = __builtin_amdgcn_mfma_f32_16x16x32_bf16(ah1, bh, acc[1][nt], 0, 0, 0);
            acc[1][nt] = __builtin_amdgcn_mfma_f32_16x16x32_bf16(ah1, bl, acc[1][nt], 0, 0, 0);
            acc[1][nt] = __builtin_amdgcn_mfma_f32_16x16x32_bf16(al1, bh, acc[1][nt], 0, 0, 0);
        }
    }

    // C/D layout (verified m89/m91): col = lane&15, row = (lane>>4)*4 + reg
    const int col = bx * 64 + lm;
    #pragma unroll
    for (int sub = 0; sub < 2; sub++) {
        const int row0 = by * 256 + wave * 32 + sub * 16 + kq * 4;
        #pragma unroll
        for (int nt = 0; nt < 4; nt++) {
            float bb = bias[col + nt * 16];
            #pragma unroll
            for (int r = 0; r < 4; r++) {
                int row = row0 + r;
                if (row < LEN) {
                    float v = acc[sub][nt][r] + bb;
                    if (mode) ((unsigned short*)C)[(size_t)row * N + col + nt * 16] = rne_bf16(v);
                    else      ((float*)C)[(size_t)row * N + col + nt * 16] = v;
                }
            }
        }
    }
}

// ---------------------------------------------------------------------------
// Deformable sampling, PERSISTENT: 2040 blocks x QPB=4 consecutive queries.
// Per query: phase 1 (lane = point): location + joint softmax + bilinear
// setup -> double-buffered LDS; ONE barrier; phase 2 (8 pts in flight,
// pt8 = lane>>2, cg = lane&3): 4 iters x 4 corner 16B gathers + butterfly.
// Double-buffer correctness: phase1(it+2) writes buffer b only after
// barrier(it+1), which every thread reaches only after its phase2(it).
// ---------------------------------------------------------------------------
__global__ __launch_bounds__(256) void sample_kernel(
    const unsigned short* __restrict__ value,  // (8160, 8, 32) bf16
    const float* __restrict__ proj,    // (8160, 768)
    const float* __restrict__ refp,    // (8160, 4, 2)
    const float* __restrict__ toff,    // (8160, 4, 2, 2)
    unsigned short* __restrict__ attn_hi,  // (8192, 256) bf16 plane
    unsigned short* __restrict__ attn_lo)
{
    const int head = threadIdx.x >> 5;
    const int lane = threadIdx.x & 31;
    __shared__ int4   s_idx[2][8][32];
    __shared__ float4 s_w[2][8][32];

    const int pt8 = lane >> 2;    // 0..7
    const int cg  = lane & 3;     // 8-channel group
    const char* vbase = (const char*)value + head * 64 + cg * 16;

    for (int it = 0; it < QPB; it++) {
        const int q = blockIdx.x * QPB + it;
        const int b = it & 1;
        const float* p = proj + (size_t)q * 768;

        // ---- phase 1 ----
        {
            const int i = lane;
            float logit, ox, oy, rx, ry;
            int l;
            if (i < 16) {
                l = i >> 2; int pt2 = i & 3;
                logit = p[256 + head * 16 + i];
                ox = p[head * 32 + l * 8 + pt2 * 2 + 0];
                oy = p[head * 32 + l * 8 + pt2 * 2 + 1];
                rx = refp[q * 8 + l * 2 + 0];
                ry = refp[q * 8 + l * 2 + 1];
            } else {
                int j = i - 16; l = j >> 2;
                int tp = j & 3, tw = tp >> 1, nt = tp & 1;
                logit = p[640 + head * 16 + j];
                ox = p[384 + head * 32 + l * 8 + tw * 4 + nt * 2 + 0];
                oy = p[384 + head * 32 + l * 8 + tw * 4 + nt * 2 + 1];
                rx = refp[q * 8 + l * 2 + 0] + toff[q * 16 + l * 4 + tw * 2 + 0];
                ry = refp[q * 8 + l * 2 + 1] + toff[q * 16 + l * 4 + tw * 2 + 1];
            }
            const int Wl = 48 >> l;
            const int Hgl = 128 >> l;
            const int st = 8192 - (8192 >> (2 * l));
            const float fW = (float)Wl, fHg = (float)Hgl;
            float x = (rx + ox / fW) * fW - 0.5f;
            float y = (ry + oy / fHg) * fHg - 0.5f;

            float mx = logit;
            #pragma unroll
            for (int off = 16; off > 0; off >>= 1)
                mx = fmaxf(mx, __shfl_xor(mx, off, 32));
            float e = expf(logit - mx);
            float s = e;
            #pragma unroll
            for (int off = 16; off > 0; off >>= 1)
                s += __shfl_xor(s, off, 32);
            float w = e / s;

            float fx = floorf(x), fy = floorf(y);
            float wx = x - fx, wy = y - fy;
            int x0 = (int)fx, y0 = (int)fy;
            int x1 = x0 + 1, y1 = y0 + 1;
            float m00 = ((unsigned)x0 < (unsigned)Wl && (unsigned)y0 < (unsigned)Hgl) ? 1.f : 0.f;
            float m10 = ((unsigned)x1 < (unsigned)Wl && (unsigned)y0 < (unsigned)Hgl) ? 1.f : 0.f;
            float m01 = ((unsigned)x0 < (unsigned)Wl && (unsigned)y1 < (unsigned)Hgl) ? 1.f : 0.f;
            float m11 = ((unsigned)x1 < (unsigned)Wl && (unsigned)y1 < (unsigned)Hgl) ? 1.f : 0.f;
            int cx0 = min(max(x0, 0), Wl - 1), cx1 = min(max(x1, 0), Wl - 1);
            int cy0 = min(max(y0, 0), Hgl - 1), cy1 = min(max(y1, 0), Hgl - 1);
            int4 ii;   // BYTE offsets (512 B per position: 8 heads x 32 ch x 2B)
            ii.x = (st + cy0 * Wl + cx0) * 512;
            ii.y = (st + cy0 * Wl + cx1) * 512;
            ii.z = (st + cy1 * Wl + cx0) * 512;
            ii.w = (st + cy1 * Wl + cx1) * 512;
            float sx0 = 1.f - wx, sy0 = 1.f - wy;
            float4 ww;
            ww.x = w * sx0 * sy0 * m00;
            ww.y = w * wx  * sy0 * m10;
            ww.z = w * sx0 * wy  * m01;
            ww.w = w * wx  * wy  * m11;
            s_idx[b][head][lane] = ii;
            s_w[b][head][lane] = ww;
        }
        __syncthreads();

        // ---- phase 2: bf16 gather, 8 points in flight per 32-lane group ----
        float acc[8] = {0.f, 0.f, 0.f, 0.f, 0.f, 0.f, 0.f, 0.f};
        #pragma unroll
        for (int i = 0; i < 4; i++) {
            int pidx = (i << 3) | pt8;
            int4 ii = s_idx[b][head][pidx];
            float4 ww = s_w[b][head][pidx];
            u16x8 v0 = *(const u16x8*)(vbase + ii.x);
            u16x8 v1 = *(const u16x8*)(vbase + ii.y);
            u16x8 v2 = *(const u16x8*)(vbase + ii.z);
            u16x8 v3 = *(const u16x8*)(vbase + ii.w);
            #pragma unroll
            for (int j = 0; j < 8; j++) {
                acc[j] = fmaf(ww.x, bf2f(v0[j]), acc[j]);
                acc[j] = fmaf(ww.y, bf2f(v1[j]), acc[j]);
                acc[j] = fmaf(ww.z, bf2f(v2[j]), acc[j]);
                acc[j] = fmaf(ww.w, bf2f(v3[j]), acc[j]);
            }
        }
        // butterfly over the 8 pt8 groups (lane bits 2..4)
        #pragma unroll
        for (int off = 4; off <= 16; off <<= 1)
            #pragma unroll
            for (int j = 0; j < 8; j++)
                acc[j] += __shfl_xor(acc[j], off, 32);

        if (pt8 == 0) {
            unsigned short h[8], l[8];
            #pragma unroll
            for (int j = 0; j < 8; j++) split_bf16(acc[j], &h[j], &l[j]);
            uint4 hv, lv;
            hv.x = h[0] | ((unsigned)h[1] << 16); hv.y = h[2] | ((unsigned)h[3] << 16);
            hv.z = h[4] | ((unsigned)h[5] << 16); hv.w = h[6] | ((unsigned)h[7] << 16);
            lv.x = l[0] | ((unsigned)l[1] << 16); lv.y = l[2] | ((unsigned)l[3] << 16);
            lv.z = l[4] | ((unsigned)l[5] << 16); lv.w = l[6] | ((unsigned)l[7] << 16);
            size_t o = (size_t)q * 256 + head * 32 + cg * 8;
            *(uint4*)(attn_hi + o) = hv;
            *(uint4*)(attn_lo + o) = lv;
        }
    }
}

// ---------------------------------------------------------------------------
extern "C" void kernel_launch(void* const* d_in, const int* in_sizes, int n_in,
                              void* d_out, int out_size, void* d_ws, size_t ws_size,
                              hipStream_t stream)
{
    const float* query = (const float*)d_in[0];
    const float* refp  = (const float*)d_in[1];
    const float* toff  = (const float*)d_in[2];
    const float* inpf  = (const float*)d_in[3];
    const float* Wv  = (const float*)d_in[6];
    const float* bv  = (const float*)d_in[7];
    const float* Ws_ = (const float*)d_in[8];
    const float* bs_ = (const float*)d_in[9];
    const float* Wa  = (const float*)d_in[10];
    const float* ba  = (const float*)d_in[11];
    const float* Wts = (const float*)d_in[12];
    const float* bts = (const float*)d_in[13];
    const float* Wta = (const float*)d_in[14];
    const float* bta = (const float*)d_in[15];
    const float* Wo  = (const float*)d_in[16];
    const float* bo  = (const float*)d_in[17];
    float* out = (float*)d_out;

    // workspace layout (~49 MB)
    unsigned short* value_bf = (unsigned short*)d_ws;          // 8160*256 bf16
    float* proj = (float*)(value_bf + (size_t)LEN * 256);      // 8160*768 f32
    float* bcat = proj + (size_t)LEN * 768;                    // 768 f32
    unsigned short* Whi = (unsigned short*)(bcat + 768);       // 1280*256
    unsigned short* Wlo = Whi + 1280 * 256;
    unsigned short* Ahi = Wlo + 1280 * 256;                    // 8192*256 (inpf, later attn)
    unsigned short* Alo = Ahi + (size_t)8192 * 256;
    unsigned short* Qhi = Alo + (size_t)8192 * 256;            // 8192*256 (query)
    unsigned short* Qlo = Qhi + (size_t)8192 * 256;

    prep_kernel<<<2203, 256, 0, stream>>>(inpf, query, Ws_, bs_, Wa, ba,
                                          Wts, bts, Wta, bta, Wv, Wo,
                                          Ahi, Alo, Qhi, Qlo, Whi, Wlo, bcat);
    // value(bf16) = inpf @ Wv + bv (bx 0..3) || proj(f32) = query @ Bcat + bcat (bx 4..15)
    gemm_mfma_dual<<<dim3(16, 32), 512, 0, stream>>>(
        Ahi, Alo, Whi, Wlo, bv, value_bf, 256, 1, 4,
        Qhi, Qlo, Whi + 256 * 256, Wlo + 256 * 256, bcat, proj, 768, 0);
    // deformable attention core -> attn planes (reuse Ahi/Alo), persistent
    sample_kernel<<<LEN / QPB, 256, 0, stream>>>(value_bf, proj, refp, toff, Ahi, Alo);
    // out(f32) = attn @ Wo + bo
    gemm_mfma_dual<<<dim3(4, 32), 512, 0, stream>>>(
        Ahi, Alo, Whi + 1024 * 256, Wlo + 1024 * 256, bo, out, 256, 0, 4,
        Ahi, Alo, Whi + 1024 * 256, Wlo + 1024 * 256, bo, out, 256, 0);
}

// Round 8
// 186.873 us; speedup vs baseline: 1.0104x; 1.0104x over previous
//
#include <hip/hip_runtime.h>

// Problem constants (hard-coded from reference: SHAPES fixed at trace time)
// Level l: W=48>>l, Hgrid=128>>l, start = 8192 - (8192 >> (2*l)); LEN=8160.

#define LEN 8160
#define NCONV8 (2 * LEN * 256 / 8)   // 522,240  (8-elem conv units)
#define NPACK8 (1280 * 256 / 8)      // 40,960   (8-elem pack units)

typedef __attribute__((ext_vector_type(8))) short bf16x8;
typedef __attribute__((ext_vector_type(8))) unsigned short u16x8;
typedef __attribute__((ext_vector_type(4))) float f32x4;

// Round-to-nearest-even fp32 -> bf16 (single)
__device__ __forceinline__ unsigned short rne_bf16(float v)
{
    unsigned u = __float_as_uint(v);
    return (unsigned short)((u + 0x7FFFu + ((u >> 16) & 1u)) >> 16);
}

// Round-to-nearest-even split of fp32 into hi+lo bf16 (bf16x3 GEMM trick).
__device__ __forceinline__ void split_bf16(float v, unsigned short* hi, unsigned short* lo)
{
    unsigned u = __float_as_uint(v);
    unsigned r = (u + 0x7FFFu + ((u >> 16) & 1u)) & 0xFFFF0000u;
    float hif = __uint_as_float(r);
    float lof = v - hif;
    unsigned ul = __float_as_uint(lof);
    unsigned rl = (ul + 0x7FFFu + ((ul >> 16) & 1u)) >> 16;
    *hi = (unsigned short)(r >> 16);
    *lo = (unsigned short)rl;
}

__device__ __forceinline__ float bf2f(unsigned short s)
{
    return __uint_as_float(((unsigned)s) << 16);
}

// ---------------------------------------------------------------------------
// prep: convA (split inpf+query into hi/lo planes, 8 elems/thread) + pack
// (weights transposed into hi/lo planes, 8 k's/thread) + concat bias.
// W row space: [0,256)=WvT [256,1024)=BcatT(Ws|Wa|Wts|Wta) [1024,1280)=WoT.
// ---------------------------------------------------------------------------
__global__ __launch_bounds__(256) void prep_kernel(
    const float* __restrict__ inpf, const float* __restrict__ query,
    const float* __restrict__ Ws, const float* __restrict__ bs,
    const float* __restrict__ Wa, const float* __restrict__ ba,
    const float* __restrict__ Wts, const float* __restrict__ bts,
    const float* __restrict__ Wta, const float* __restrict__ bta,
    const float* __restrict__ Wv, const float* __restrict__ Wo,
    unsigned short* __restrict__ Ahi, unsigned short* __restrict__ Alo,
    unsigned short* __restrict__ Qhi, unsigned short* __restrict__ Qlo,
    unsigned short* __restrict__ Whi, unsigned short* __restrict__ Wlo,
    float* __restrict__ bcat)
{
    int idx = blockIdx.x * 256 + threadIdx.x;
    if (idx < NCONV8) {
        int which = (idx >= NCONV8 / 2) ? 1 : 0;
        int off = (idx - which * (NCONV8 / 2)) * 8;
        const float* src = which ? query : inpf;
        float4 a = *(const float4*)(src + off);
        float4 b = *(const float4*)(src + off + 4);
        unsigned short h[8], l[8];
        split_bf16(a.x, &h[0], &l[0]); split_bf16(a.y, &h[1], &l[1]);
        split_bf16(a.z, &h[2], &l[2]); split_bf16(a.w, &h[3], &l[3]);
        split_bf16(b.x, &h[4], &l[4]); split_bf16(b.y, &h[5], &l[5]);
        split_bf16(b.z, &h[6], &l[6]); split_bf16(b.w, &h[7], &l[7]);
        uint4 hv, lv;
        hv.x = h[0] | ((unsigned)h[1] << 16); hv.y = h[2] | ((unsigned)h[3] << 16);
        hv.z = h[4] | ((unsigned)h[5] << 16); hv.w = h[6] | ((unsigned)h[7] << 16);
        lv.x = l[0] | ((unsigned)l[1] << 16); lv.y = l[2] | ((unsigned)l[3] << 16);
        lv.z = l[4] | ((unsigned)l[5] << 16); lv.w = l[6] | ((unsigned)l[7] << 16);
        if (which) { *(uint4*)(Qhi + off) = hv; *(uint4*)(Qlo + off) = lv; }
        else       { *(uint4*)(Ahi + off) = hv; *(uint4*)(Alo + off) = lv; }
    } else if (idx < NCONV8 + NPACK8) {
        int j8 = idx - NCONV8;
        int n = j8 >> 5;
        int k0 = (j8 & 31) << 3;
        unsigned short h[8], l[8];
        #pragma unroll
        for (int t = 0; t < 8; t++) {
            int k = k0 + t;
            float v;
            if (n < 256) v = Wv[k * 256 + n];
            else if (n < 1024) {
                int j = n - 256;
                if (j < 256)      v = Ws [k * 256 + j];
                else if (j < 384) v = Wa [k * 128 + (j - 256)];
                else if (j < 640) v = Wts[k * 256 + (j - 384)];
                else              v = Wta[k * 128 + (j - 640)];
            } else v = Wo[k * 256 + (n - 1024)];
            split_bf16(v, &h[t], &l[t]);
        }
        uint4 hv, lv;
        hv.x = h[0] | ((unsigned)h[1] << 16); hv.y = h[2] | ((unsigned)h[3] << 16);
        hv.z = h[4] | ((unsigned)h[5] << 16); hv.w = h[6] | ((unsigned)h[7] << 16);
        lv.x = l[0] | ((unsigned)l[1] << 16); lv.y = l[2] | ((unsigned)l[3] << 16);
        lv.z = l[4] | ((unsigned)l[5] << 16); lv.w = l[6] | ((unsigned)l[7] << 16);
        *(uint4*)(Whi + n * 256 + k0) = hv;
        *(uint4*)(Wlo + n * 256 + k0) = lv;
    } else if (idx < NCONV8 + NPACK8 + 768) {
        int j = idx - (NCONV8 + NPACK8);
        float v;
        if (j < 256)      v = bs[j];
        else if (j < 384) v = ba[j - 256];
        else if (j < 640) v = bts[j - 384];
        else              v = bta[j - 640];
        bcat[j] = v;
    }
}

// ---------------------------------------------------------------------------
// bf16x3 MFMA GEMM, dual problem-set. Tile 128(M)x64(N), 256 thr = 4 waves,
// wave owns 32 rows (2 x 16-row subtiles). K processed in 2 chunks of 128;
// per chunk B (both planes) staged in frag-order LDS (32 KB -> 4 blocks/CU).
// Staging: 2048 slots x 16 B per chunk = 8 iterations x 256 threads.
// mode: 0 = f32 row-major store; 1 = bf16 store into (head,pos,32ch) planes.
// ---------------------------------------------------------------------------
__global__ __launch_bounds__(256) void gemm_mfma_dual(
    const unsigned short* __restrict__ A0hi, const unsigned short* __restrict__ A0lo,
    const unsigned short* __restrict__ B0hi, const unsigned short* __restrict__ B0lo,
    const float* __restrict__ bias0, void* __restrict__ C0, int N0, int mode0, int nbx0,
    const unsigned short* __restrict__ A1hi, const unsigned short* __restrict__ A1lo,
    const unsigned short* __restrict__ B1hi, const unsigned short* __restrict__ B1lo,
    const float* __restrict__ bias1, void* __restrict__ C1, int N1, int mode1)
{
    // frag-order LDS per chunk: [plane][kt(4)][nt(4)][lane(64)][8 bf16] = 32 KB
    __shared__ unsigned short Bf[2 * 4 * 4 * 64 * 8];
    const int tid = threadIdx.x;
    const int wave = tid >> 6, lane = tid & 63;
    int bx = blockIdx.x;
    const int by = blockIdx.y;

    const unsigned short *Ahi, *Alo, *Bhi, *Blo;
    const float* bias; void* C; int N, mode;
    if (bx < nbx0) {
        Ahi = A0hi; Alo = A0lo; Bhi = B0hi; Blo = B0lo;
        bias = bias0; C = C0; N = N0; mode = mode0;
    } else {
        bx -= nbx0;
        Ahi = A1hi; Alo = A1lo; Bhi = B1hi; Blo = B1lo;
        bias = bias1; C = C1; N = N1; mode = mode1;
    }

    const int lm = lane & 15;     // m within 16-tile / C column
    const int kq = lane >> 4;     // k-quad (0..3)
    const int m0 = by * 128 + wave * 32 + lm;
    const unsigned short* aHp = Ahi + (size_t)m0 * 256 + kq * 8;
    const unsigned short* aLp = Alo + (size_t)m0 * 256 + kq * 8;

    f32x4 acc[2][4] = {};
    #pragma unroll
    for (int chunk = 0; chunk < 2; chunk++) {
        // stage chunk's B tile (both planes): 2048 slots x 16 B
        #pragma unroll
        for (int t = 0; t < 8; t++) {
            int f = t * 256 + tid;                  // [0, 2048)
            int ln = f & 63, nt = (f >> 6) & 3, kt = (f >> 8) & 3, pl = f >> 10;
            const unsigned short* src = (pl ? Blo : Bhi)
                + (size_t)(bx * 64 + nt * 16 + (ln & 15)) * 256
                + chunk * 128 + kt * 32 + (ln >> 4) * 8;
            *(uint4*)(&Bf[(size_t)f * 8]) = *(const uint4*)src;
        }
        __syncthreads();
        #pragma unroll
        for (int kt = 0; kt < 4; kt++) {
            const int ko = chunk * 128 + kt * 32;
            bf16x8 ah0 = *(const bf16x8*)(aHp + ko);
            bf16x8 al0 = *(const bf16x8*)(aLp + ko);
            bf16x8 ah1 = *(const bf16x8*)(aHp + 16 * 256 + ko);
            bf16x8 al1 = *(const bf16x8*)(aLp + 16 * 256 + ko);
            #pragma unroll
            for (int nt = 0; nt < 4; nt++) {
                const int fb = (kt * 4 + nt) * 64 + lane;
                bf16x8 bh = *(const bf16x8*)(&Bf[(size_t)fb * 8]);
                bf16x8 bl = *(const bf16x8*)(&Bf[(size_t)(fb + 1024) * 8]);
                acc[0][nt] = __builtin_amdgcn_mfma_f32_16x16x32_bf16(ah0, bh, acc[0][nt], 0, 0, 0);
                acc[0][nt] = __builtin_amdgcn_mfma_f32_16x16x32_bf16(ah0, bl, acc[0][nt], 0, 0, 0);
                acc[0][nt] = __builtin_amdgcn_mfma_f32_16x16x32_bf16(al0, bh, acc[0][nt], 0, 0, 0);
                acc[1][nt] = __builtin_amdgcn_mfma_f32_16x16x32_bf16(ah1, bh, acc[1][nt], 0, 0, 0);
                acc[1][nt] = __builtin_amdgcn_mfma_f32_16x16x32_bf16(ah1, bl, acc[1][nt], 0, 0, 0);
                acc[1][nt] = __builtin_amdgcn_mfma_f32_16x16x32_bf16(al1, bh, acc[1][nt], 0, 0, 0);
            }
        }
        __syncthreads();
    }

    // C/D layout (verified m89/m91): col = lane&15, row = (lane>>4)*4 + reg
    const int col = bx * 64 + lm;
    #pragma unroll
    for (int sub = 0; sub < 2; sub++) {
        const int row0 = by * 128 + wave * 32 + sub * 16 + kq * 4;
        #pragma unroll
        for (int nt = 0; nt < 4; nt++) {
            int c = col + nt * 16;
            float bb = bias[c];
            #pragma unroll
            for (int r = 0; r < 4; r++) {
                int row = row0 + r;
                if (row < LEN) {
                    float v = acc[sub][nt][r] + bb;
                    if (mode) {
                        // value plane layout: head = c>>5, ch = c&31
                        ((unsigned short*)C)[(size_t)(c >> 5) * 8192 * 32
                                             + (size_t)row * 32 + (c & 31)] = rne_bf16(v);
                    } else {
                        ((float*)C)[(size_t)row * N + c] = v;
                    }
                }
            }
        }
    }
}

// ---------------------------------------------------------------------------
// Deformable sampling. One block per query; 8 heads x 32 lanes.
// Value layout (head, pos, 32ch): the two x-adjacent corners of a y-row are
// CONTIGUOUS 128 B -> one gather covers both (8 lanes x 16 B).
// Phase 1: lane = point. Location + joint softmax + x-pair bilinear setup:
//   xb = clamp(x0,0,W-2); per-half x-weights aL/aR absorb clamps & masks;
//   per point: 2 row byte-offsets + 4 weights (L/R x y0/y1) -> LDS.
// Phase 2: pt4 = lane>>3 (4 pts in flight), half = (lane>>2)&1, cg = lane&3.
//   8 iters x 2 row gathers (128 B per 8-lane group) + 16 fma.
//   Butterfly xor{4,8,16}: xor4 merges x-halves, xor8/16 merge points.
// ---------------------------------------------------------------------------
__global__ __launch_bounds__(256) void sample_kernel(
    const unsigned short* __restrict__ value,  // (8, 8192, 32) bf16 planes
    const float* __restrict__ proj,    // (8160, 768)
    const float* __restrict__ refp,    // (8160, 4, 2)
    const float* __restrict__ toff,    // (8160, 4, 2, 2)
    unsigned short* __restrict__ attn_hi,  // (8192, 256) bf16 plane
    unsigned short* __restrict__ attn_lo)
{
    const int q = blockIdx.x;
    const int head = threadIdx.x >> 5;
    const int lane = threadIdx.x & 31;
    __shared__ int2   s_row[8][32];
    __shared__ float4 s_w[8][32];

    const float* p = proj + (size_t)q * 768;

    // ---- phase 1 ----
    {
        const int i = lane;
        float logit, ox, oy, rx, ry;
        int l;
        if (i < 16) {
            l = i >> 2; int pt2 = i & 3;
            logit = p[256 + head * 16 + i];
            ox = p[head * 32 + l * 8 + pt2 * 2 + 0];
            oy = p[head * 32 + l * 8 + pt2 * 2 + 1];
            rx = refp[q * 8 + l * 2 + 0];
            ry = refp[q * 8 + l * 2 + 1];
        } else {
            int j = i - 16; l = j >> 2;
            int tp = j & 3, tw = tp >> 1, nt = tp & 1;
            logit = p[640 + head * 16 + j];
            ox = p[384 + head * 32 + l * 8 + tw * 4 + nt * 2 + 0];
            oy = p[384 + head * 32 + l * 8 + tw * 4 + nt * 2 + 1];
            rx = refp[q * 8 + l * 2 + 0] + toff[q * 16 + l * 4 + tw * 2 + 0];
            ry = refp[q * 8 + l * 2 + 1] + toff[q * 16 + l * 4 + tw * 2 + 1];
        }
        const int Wl = 48 >> l;
        const int Hgl = 128 >> l;
        const int st = 8192 - (8192 >> (2 * l));
        const float fW = (float)Wl, fHg = (float)Hgl;
        float x = (rx + ox / fW) * fW - 0.5f;
        float y = (ry + oy / fHg) * fHg - 0.5f;

        float mx = logit;
        #pragma unroll
        for (int off = 16; off > 0; off >>= 1)
            mx = fmaxf(mx, __shfl_xor(mx, off, 32));
        float e = expf(logit - mx);
        float s = e;
        #pragma unroll
        for (int off = 16; off > 0; off >>= 1)
            s += __shfl_xor(s, off, 32);
        float w = e / s;

        float fx = floorf(x), fy = floorf(y);
        float wx = x - fx, wy = y - fy;
        int x0 = (int)fx, y0 = (int)fy;
        int x1 = x0 + 1, y1 = y0 + 1;
        float mx0 = ((unsigned)x0 < (unsigned)Wl) ? 1.f : 0.f;
        float mx1 = ((unsigned)x1 < (unsigned)Wl) ? 1.f : 0.f;
        float my0 = ((unsigned)y0 < (unsigned)Hgl) ? 1.f : 0.f;
        float my1 = ((unsigned)y1 < (unsigned)Hgl) ? 1.f : 0.f;
        int cx0 = min(max(x0, 0), Wl - 1), cx1 = min(max(x1, 0), Wl - 1);
        int cy0 = min(max(y0, 0), Hgl - 1), cy1 = min(max(y1, 0), Hgl - 1);
        int xb = min(max(x0, 0), Wl - 2);
        float sx0 = 1.f - wx, sy0 = 1.f - wy;
        // per-half x weights (absorb clamping: each clamped corner lands on
        // whichever loaded half equals its clamped position)
        float aL = (cx0 == xb     ? sx0 * mx0 : 0.f) + (cx1 == xb     ? wx * mx1 : 0.f);
        float aR = (cx0 == xb + 1 ? sx0 * mx0 : 0.f) + (cx1 == xb + 1 ? wx * mx1 : 0.f);
        float by0 = sy0 * my0, by1 = wy * my1;
        int2 rr;   // BYTE offsets within a head plane (64 B per position)
        rr.x = (st + cy0 * Wl + xb) * 64;
        rr.y = (st + cy1 * Wl + xb) * 64;
        float4 ww;
        ww.x = w * aL * by0;   // y0 row, left half
        ww.y = w * aR * by0;   // y0 row, right half
        ww.z = w * aL * by1;   // y1 row, left half
        ww.w = w * aR * by1;   // y1 row, right half
        s_row[head][lane] = rr;
        s_w[head][lane] = ww;
    }
    __syncthreads();

    // ---- phase 2: x-pair gathers, 4 points in flight per 32-lane group ----
    const int pt4  = lane >> 3;        // 0..3
    const int half = (lane >> 2) & 1;  // x-half within the 128B pair
    const int cg   = lane & 3;         // 8-channel group
    const char* vbase = (const char*)value + head * (8192 * 64) + half * 64 + cg * 16;
    float acc[8] = {0.f, 0.f, 0.f, 0.f, 0.f, 0.f, 0.f, 0.f};
    #pragma unroll
    for (int i = 0; i < 8; i++) {
        int pidx = (i << 2) | pt4;
        int2 rr = s_row[head][pidx];
        float4 ww = s_w[head][pidx];
        u16x8 v0 = *(const u16x8*)(vbase + rr.x);
        u16x8 v1 = *(const u16x8*)(vbase + rr.y);
        float w0 = half ? ww.y : ww.x;
        float w1 = half ? ww.w : ww.z;
        #pragma unroll
        for (int j = 0; j < 8; j++) {
            acc[j] = fmaf(w0, bf2f(v0[j]), acc[j]);
            acc[j] = fmaf(w1, bf2f(v1[j]), acc[j]);
        }
    }
    // butterfly: xor4 merges x-halves, xor8/16 merge the 4 points
    #pragma unroll
    for (int off = 4; off <= 16; off <<= 1)
        #pragma unroll
        for (int j = 0; j < 8; j++)
            acc[j] += __shfl_xor(acc[j], off, 32);

    if (lane < 4) {
        unsigned short h[8], l[8];
        #pragma unroll
        for (int j = 0; j < 8; j++) split_bf16(acc[j], &h[j], &l[j]);
        uint4 hv, lv;
        hv.x = h[0] | ((unsigned)h[1] << 16); hv.y = h[2] | ((unsigned)h[3] << 16);
        hv.z = h[4] | ((unsigned)h[5] << 16); hv.w = h[6] | ((unsigned)h[7] << 16);
        lv.x = l[0] | ((unsigned)l[1] << 16); lv.y = l[2] | ((unsigned)l[3] << 16);
        lv.z = l[4] | ((unsigned)l[5] << 16); lv.w = l[6] | ((unsigned)l[7] << 16);
        size_t o = (size_t)q * 256 + head * 32 + cg * 8;
        *(uint4*)(attn_hi + o) = hv;
        *(uint4*)(attn_lo + o) = lv;
    }
}

// ---------------------------------------------------------------------------
extern "C" void kernel_launch(void* const* d_in, const int* in_sizes, int n_in,
                              void* d_out, int out_size, void* d_ws, size_t ws_size,
                              hipStream_t stream)
{
    const float* query = (const float*)d_in[0];
    const float* refp  = (const float*)d_in[1];
    const float* toff  = (const float*)d_in[2];
    const float* inpf  = (const float*)d_in[3];
    const float* Wv  = (const float*)d_in[6];
    const float* bv  = (const float*)d_in[7];
    const float* Ws_ = (const float*)d_in[8];
    const float* bs_ = (const float*)d_in[9];
    const float* Wa  = (const float*)d_in[10];
    const float* ba  = (const float*)d_in[11];
    const float* Wts = (const float*)d_in[12];
    const float* bts = (const float*)d_in[13];
    const float* Wta = (const float*)d_in[14];
    const float* bta = (const float*)d_in[15];
    const float* Wo  = (const float*)d_in[16];
    const float* bo  = (const float*)d_in[17];
    float* out = (float*)d_out;

    // workspace layout (~48 MB)
    unsigned short* value_bf = (unsigned short*)d_ws;          // 8 x 8192 x 32 bf16 planes
    float* proj = (float*)(value_bf + (size_t)8 * 8192 * 32);  // 8160*768 f32
    float* bcat = proj + (size_t)LEN * 768;                    // 768 f32
    unsigned short* Whi = (unsigned short*)(bcat + 768);       // 1280*256
    unsigned short* Wlo = Whi + 1280 * 256;
    unsigned short* Ahi = Wlo + 1280 * 256;                    // 8192*256 (inpf, later attn)
    unsigned short* Alo = Ahi + (size_t)8192 * 256;
    unsigned short* Qhi = Alo + (size_t)8192 * 256;            // 8192*256 (query)
    unsigned short* Qlo = Qhi + (size_t)8192 * 256;

    prep_kernel<<<2203, 256, 0, stream>>>(inpf, query, Ws_, bs_, Wa, ba,
                                          Wts, bts, Wta, bta, Wv, Wo,
                                          Ahi, Alo, Qhi, Qlo, Whi, Wlo, bcat);
    // value(bf16 planes) = inpf @ Wv + bv (bx 0..3) ||
    // proj(f32) = query @ Bcat + bcat (bx 4..15); grid (16, 64) = 1024 blocks
    gemm_mfma_dual<<<dim3(16, 64), 256, 0, stream>>>(
        Ahi, Alo, Whi, Wlo, bv, value_bf, 256, 1, 4,
        Qhi, Qlo, Whi + 256 * 256, Wlo + 256 * 256, bcat, proj, 768, 0);
    // deformable attention core -> attn planes (reuse Ahi/Alo)
    sample_kernel<<<LEN, 256, 0, stream>>>(value_bf, proj, refp, toff, Ahi, Alo);
    // out(f32) = attn @ Wo + bo; grid (4, 64) = 256 blocks
    gemm_mfma_dual<<<dim3(4, 64), 256, 0, stream>>>(
        Ahi, Alo, Whi + 1024 * 256, Wlo + 1024 * 256, bo, out, 256, 0, 4,
        Ahi, Alo, Whi + 1024 * 256, Wlo + 1024 * 256, bo, out, 256, 0);
}

// Round 10
// 173.909 us; speedup vs baseline: 1.0857x; 1.0745x over previous
//
#include <hip/hip_runtime.h>

// Problem constants (hard-coded from reference: SHAPES fixed at trace time)
// Level l: W=48>>l, Hgrid=128>>l, start = 8192 - (8192 >> (2*l)); LEN=8160.

#define LEN 8160
#define NPACK8 (1280 * 256 / 8)      // 40,960 (8-elem pack units)

typedef __attribute__((ext_vector_type(8))) short bf16x8;
typedef __attribute__((ext_vector_type(8))) unsigned short u16x8;
typedef __attribute__((ext_vector_type(4))) float f32x4;

__device__ __forceinline__ unsigned short rne_bf16(float v)
{
    unsigned u = __float_as_uint(v);
    return (unsigned short)((u + 0x7FFFu + ((u >> 16) & 1u)) >> 16);
}

// Round-to-nearest-even split of fp32 into hi+lo bf16 (bf16x3 GEMM trick).
__device__ __forceinline__ void split_bf16(float v, unsigned short* hi, unsigned short* lo)
{
    unsigned u = __float_as_uint(v);
    unsigned r = (u + 0x7FFFu + ((u >> 16) & 1u)) & 0xFFFF0000u;
    float hif = __uint_as_float(r);
    float lof = v - hif;
    unsigned ul = __float_as_uint(lof);
    unsigned rl = (ul + 0x7FFFu + ((ul >> 16) & 1u)) >> 16;
    *hi = (unsigned short)(r >> 16);
    *lo = (unsigned short)rl;
}

__device__ __forceinline__ float bf2f(unsigned short s)
{
    return __uint_as_float(((unsigned)s) << 16);
}

// Inline split of 8 consecutive f32 A elements into hi/lo bf16x8 fragments.
__device__ __forceinline__ void splitA8(const float* a, bf16x8* hi, bf16x8* lo)
{
    float4 x = *(const float4*)a;
    float4 y = *(const float4*)(a + 4);
    unsigned short h[8], l[8];
    split_bf16(x.x, &h[0], &l[0]); split_bf16(x.y, &h[1], &l[1]);
    split_bf16(x.z, &h[2], &l[2]); split_bf16(x.w, &h[3], &l[3]);
    split_bf16(y.x, &h[4], &l[4]); split_bf16(y.y, &h[5], &l[5]);
    split_bf16(y.z, &h[6], &l[6]); split_bf16(y.w, &h[7], &l[7]);
    bf16x8 hv, lv;
    #pragma unroll
    for (int i = 0; i < 8; i++) { hv[i] = (short)h[i]; lv[i] = (short)l[i]; }
    *hi = hv; *lo = lv;
}

// ---------------------------------------------------------------------------
// prep: pack all weights transposed (B^T[n][k]) into hi/lo bf16 planes +
// concat bias. Row space: [0,256)=WvT [256,1024)=BcatT [1024,1280)=WoT.
// ---------------------------------------------------------------------------
__global__ __launch_bounds__(256) void prep_kernel(
    const float* __restrict__ Ws, const float* __restrict__ bs,
    const float* __restrict__ Wa, const float* __restrict__ ba,
    const float* __restrict__ Wts, const float* __restrict__ bts,
    const float* __restrict__ Wta, const float* __restrict__ bta,
    const float* __restrict__ Wv, const float* __restrict__ Wo,
    unsigned short* __restrict__ Whi, unsigned short* __restrict__ Wlo,
    float* __restrict__ bcat)
{
    int idx = blockIdx.x * 256 + threadIdx.x;
    if (idx < NPACK8) {
        int n = idx >> 5;
        int k0 = (idx & 31) << 3;
        unsigned short h[8], l[8];
        #pragma unroll
        for (int t = 0; t < 8; t++) {
            int k = k0 + t;
            float v;
            if (n < 256) v = Wv[k * 256 + n];
            else if (n < 1024) {
                int j = n - 256;
                if (j < 256)      v = Ws [k * 256 + j];
                else if (j < 384) v = Wa [k * 128 + (j - 256)];
                else if (j < 640) v = Wts[k * 256 + (j - 384)];
                else              v = Wta[k * 128 + (j - 640)];
            } else v = Wo[k * 256 + (n - 1024)];
            split_bf16(v, &h[t], &l[t]);
        }
        uint4 hv, lv;
        hv.x = h[0] | ((unsigned)h[1] << 16); hv.y = h[2] | ((unsigned)h[3] << 16);
        hv.z = h[4] | ((unsigned)h[5] << 16); hv.w = h[6] | ((unsigned)h[7] << 16);
        lv.x = l[0] | ((unsigned)l[1] << 16); lv.y = l[2] | ((unsigned)l[3] << 16);
        lv.z = l[4] | ((unsigned)l[5] << 16); lv.w = l[6] | ((unsigned)l[7] << 16);
        *(uint4*)(Whi + n * 256 + k0) = hv;
        *(uint4*)(Wlo + n * 256 + k0) = lv;
    } else if (idx < NPACK8 + 768) {
        int j = idx - NPACK8;
        float v;
        if (j < 256)      v = bs[j];
        else if (j < 384) v = ba[j - 256];
        else if (j < 640) v = bts[j - 384];
        else              v = bta[j - 640];
        bcat[j] = v;
    }
}

// ---------------------------------------------------------------------------
// bf16x3 MFMA GEMM, dual problem-set, A read as f32 + inline register split.
// Tile 128(M)x64(N), 256 thr = 4 waves, wave owns 32 rows (2 x 16-row
// subtiles). K=256 in 2 chunks of 128; B (hi+lo planes) staged per chunk in
// frag-order LDS (32 KB). A-row loads clamped to LEN-1 (stores guarded).
// mode: 0 = f32 row-major store; 1 = bf16 store into (head,pos,32ch) planes.
// ---------------------------------------------------------------------------
__global__ __launch_bounds__(256) void gemm_mfma_dual(
    const float* __restrict__ A0,
    const unsigned short* __restrict__ B0hi, const unsigned short* __restrict__ B0lo,
    const float* __restrict__ bias0, void* __restrict__ C0, int N0, int mode0, int nbx0,
    const float* __restrict__ A1,
    const unsigned short* __restrict__ B1hi, const unsigned short* __restrict__ B1lo,
    const float* __restrict__ bias1, void* __restrict__ C1, int N1, int mode1)
{
    // frag-order LDS per chunk: [plane][kt(4)][nt(4)][lane(64)][8 bf16] = 32 KB
    __shared__ unsigned short Bf[2 * 4 * 4 * 64 * 8];
    const int tid = threadIdx.x;
    const int wave = tid >> 6, lane = tid & 63;
    int bx = blockIdx.x;
    const int by = blockIdx.y;

    const float* A;
    const unsigned short *Bhi, *Blo;
    const float* bias; void* C; int N, mode;
    if (bx < nbx0) {
        A = A0; Bhi = B0hi; Blo = B0lo;
        bias = bias0; C = C0; N = N0; mode = mode0;
    } else {
        bx -= nbx0;
        A = A1; Bhi = B1hi; Blo = B1lo;
        bias = bias1; C = C1; N = N1; mode = mode1;
    }

    const int lm = lane & 15;     // m within 16-tile / C column
    const int kq = lane >> 4;     // k-quad (0..3)
    const int m0 = by * 128 + wave * 32 + lm;
    const int ra = min(m0, LEN - 1);            // clamped A rows (loads in-bounds)
    const int rb = min(m0 + 16, LEN - 1);
    const float* aP0 = A + (size_t)ra * 256 + kq * 8;
    const float* aP1 = A + (size_t)rb * 256 + kq * 8;

    f32x4 acc[2][4] = {};
    #pragma unroll
    for (int chunk = 0; chunk < 2; chunk++) {
        // stage chunk's B tile (both planes): 2048 slots x 16 B
        #pragma unroll
        for (int t = 0; t < 8; t++) {
            int f = t * 256 + tid;                  // [0, 2048)
            int ln = f & 63, nt = (f >> 6) & 3, kt = (f >> 8) & 3, pl = f >> 10;
            const unsigned short* src = (pl ? Blo : Bhi)
                + (size_t)(bx * 64 + nt * 16 + (ln & 15)) * 256
                + chunk * 128 + kt * 32 + (ln >> 4) * 8;
            *(uint4*)(&Bf[(size_t)f * 8]) = *(const uint4*)src;
        }
        __syncthreads();
        #pragma unroll
        for (int kt = 0; kt < 4; kt++) {
            const int ko = chunk * 128 + kt * 32;
            bf16x8 ah0, al0, ah1, al1;
            splitA8(aP0 + ko, &ah0, &al0);
            splitA8(aP1 + ko, &ah1, &al1);
            #pragma unroll
            for (int nt = 0; nt < 4; nt++) {
                const int fb = (kt * 4 + nt) * 64 + lane;
                bf16x8 bh = *(const bf16x8*)(&Bf[(size_t)fb * 8]);
                bf16x8 bl = *(const bf16x8*)(&Bf[(size_t)(fb + 1024) * 8]);
                acc[0][nt] = __builtin_amdgcn_mfma_f32_16x16x32_bf16(ah0, bh, acc[0][nt], 0, 0, 0);
                acc[0][nt] = __builtin_amdgcn_mfma_f32_16x16x32_bf16(ah0, bl, acc[0][nt], 0, 0, 0);
                acc[0][nt] = __builtin_amdgcn_mfma_f32_16x16x32_bf16(al0, bh, acc[0][nt], 0, 0, 0);
                acc[1][nt] = __builtin_amdgcn_mfma_f32_16x16x32_bf16(ah1, bh, acc[1][nt], 0, 0, 0);
                acc[1][nt] = __builtin_amdgcn_mfma_f32_16x16x32_bf16(ah1, bl, acc[1][nt], 0, 0, 0);
                acc[1][nt] = __builtin_amdgcn_mfma_f32_16x16x32_bf16(al1, bh, acc[1][nt], 0, 0, 0);
            }
        }
        __syncthreads();
    }

    // C/D layout (verified m89/m91): col = lane&15, row = (lane>>4)*4 + reg
    const int col = bx * 64 + lm;
    #pragma unroll
    for (int sub = 0; sub < 2; sub++) {
        const int row0 = by * 128 + wave * 32 + sub * 16 + kq * 4;
        #pragma unroll
        for (int nt = 0; nt < 4; nt++) {
            int c = col + nt * 16;
            float bb = bias[c];
            #pragma unroll
            for (int r = 0; r < 4; r++) {
                int row = row0 + r;
                if (row < LEN) {
                    float v = acc[sub][nt][r] + bb;
                    if (mode) {
                        // value plane layout: head = c>>5, ch = c&31
                        ((unsigned short*)C)[(size_t)(c >> 5) * 8192 * 32
                                             + (size_t)row * 32 + (c & 31)] = rne_bf16(v);
                    } else {
                        ((float*)C)[(size_t)row * N + c] = v;
                    }
                }
            }
        }
    }
}

// ---------------------------------------------------------------------------
// Deformable sampling. One block per query; 8 heads x 32 lanes.
// Value layout (head, pos, 32ch): the two x-adjacent corners of a y-row are
// CONTIGUOUS 128 B -> one gather covers both (8 lanes x 16 B).
// Phase 1: lane = point -> location, joint softmax, x-pair bilinear setup.
// Phase 2: pt4 = lane>>3, half = (lane>>2)&1, cg = lane&3; 8 iters x 2 row
// gathers + 16 fma; butterfly xor{4,8,16}. Epilogue writes attn as f32.
// ---------------------------------------------------------------------------
__global__ __launch_bounds__(256) void sample_kernel(
    const unsigned short* __restrict__ value,  // (8, 8192, 32) bf16 planes
    const float* __restrict__ proj,    // (8160, 768)
    const float* __restrict__ refp,    // (8160, 4, 2)
    const float* __restrict__ toff,    // (8160, 4, 2, 2)
    float* __restrict__ attn)          // (8160, 256) f32
{
    const int q = blockIdx.x;
    const int head = threadIdx.x >> 5;
    const int lane = threadIdx.x & 31;
    __shared__ int2   s_row[8][32];
    __shared__ float4 s_w[8][32];

    const float* p = proj + (size_t)q * 768;

    // ---- phase 1 ----
    {
        const int i = lane;
        float logit, ox, oy, rx, ry;
        int l;
        if (i < 16) {
            l = i >> 2; int pt2 = i & 3;
            logit = p[256 + head * 16 + i];
            ox = p[head * 32 + l * 8 + pt2 * 2 + 0];
            oy = p[head * 32 + l * 8 + pt2 * 2 + 1];
            rx = refp[q * 8 + l * 2 + 0];
            ry = refp[q * 8 + l * 2 + 1];
        } else {
            int j = i - 16; l = j >> 2;
            int tp = j & 3, tw = tp >> 1, nt = tp & 1;
            logit = p[640 + head * 16 + j];
            ox = p[384 + head * 32 + l * 8 + tw * 4 + nt * 2 + 0];
            oy = p[384 + head * 32 + l * 8 + tw * 4 + nt * 2 + 1];
            rx = refp[q * 8 + l * 2 + 0] + toff[q * 16 + l * 4 + tw * 2 + 0];
            ry = refp[q * 8 + l * 2 + 1] + toff[q * 16 + l * 4 + tw * 2 + 1];
        }
        const int Wl = 48 >> l;
        const int Hgl = 128 >> l;
        const int st = 8192 - (8192 >> (2 * l));
        const float fW = (float)Wl, fHg = (float)Hgl;
        float x = (rx + ox / fW) * fW - 0.5f;
        float y = (ry + oy / fHg) * fHg - 0.5f;

        float mx = logit;
        #pragma unroll
        for (int off = 16; off > 0; off >>= 1)
            mx = fmaxf(mx, __shfl_xor(mx, off, 32));
        float e = expf(logit - mx);
        float s = e;
        #pragma unroll
        for (int off = 16; off > 0; off >>= 1)
            s += __shfl_xor(s, off, 32);
        float w = e / s;

        float fx = floorf(x), fy = floorf(y);
        float wx = x - fx, wy = y - fy;
        int x0 = (int)fx, y0 = (int)fy;
        int x1 = x0 + 1, y1 = y0 + 1;
        float mx0 = ((unsigned)x0 < (unsigned)Wl) ? 1.f : 0.f;
        float mx1 = ((unsigned)x1 < (unsigned)Wl) ? 1.f : 0.f;
        float my0 = ((unsigned)y0 < (unsigned)Hgl) ? 1.f : 0.f;
        float my1 = ((unsigned)y1 < (unsigned)Hgl) ? 1.f : 0.f;
        int cx0 = min(max(x0, 0), Wl - 1), cx1 = min(max(x1, 0), Wl - 1);
        int cy0 = min(max(y0, 0), Hgl - 1), cy1 = min(max(y1, 0), Hgl - 1);
        int xb = min(max(x0, 0), Wl - 2);
        float sx0 = 1.f - wx, sy0 = 1.f - wy;
        // per-half x weights (absorb clamping: each clamped corner lands on
        // whichever loaded half equals its clamped position)
        float aL = (cx0 == xb     ? sx0 * mx0 : 0.f) + (cx1 == xb     ? wx * mx1 : 0.f);
        float aR = (cx0 == xb + 1 ? sx0 * mx0 : 0.f) + (cx1 == xb + 1 ? wx * mx1 : 0.f);
        float by0 = sy0 * my0, by1 = wy * my1;
        int2 rr;   // BYTE offsets within a head plane (64 B per position)
        rr.x = (st + cy0 * Wl + xb) * 64;
        rr.y = (st + cy1 * Wl + xb) * 64;
        float4 ww;
        ww.x = w * aL * by0;   // y0 row, left half
        ww.y = w * aR * by0;   // y0 row, right half
        ww.z = w * aL * by1;   // y1 row, left half
        ww.w = w * aR * by1;   // y1 row, right half
        s_row[head][lane] = rr;
        s_w[head][lane] = ww;
    }
    __syncthreads();

    // ---- phase 2: x-pair gathers, 4 points in flight per 32-lane group ----
    const int pt4  = lane >> 3;        // 0..3
    const int half = (lane >> 2) & 1;  // x-half within the 128B pair
    const int cg   = lane & 3;         // 8-channel group
    const char* vbase = (const char*)value + head * (8192 * 64) + half * 64 + cg * 16;
    float acc[8] = {0.f, 0.f, 0.f, 0.f, 0.f, 0.f, 0.f, 0.f};
    #pragma unroll
    for (int i = 0; i < 8; i++) {
        int pidx = (i << 2) | pt4;
        int2 rr = s_row[head][pidx];
        float4 ww = s_w[head][pidx];
        u16x8 v0 = *(const u16x8*)(vbase + rr.x);
        u16x8 v1 = *(const u16x8*)(vbase + rr.y);
        float w0 = half ? ww.y : ww.x;
        float w1 = half ? ww.w : ww.z;
        #pragma unroll
        for (int j = 0; j < 8; j++) {
            acc[j] = fmaf(w0, bf2f(v0[j]), acc[j]);
            acc[j] = fmaf(w1, bf2f(v1[j]), acc[j]);
        }
    }
    // butterfly: xor4 merges x-halves, xor8/16 merge the 4 points
    #pragma unroll
    for (int off = 4; off <= 16; off <<= 1)
        #pragma unroll
        for (int j = 0; j < 8; j++)
            acc[j] += __shfl_xor(acc[j], off, 32);

    if (lane < 4) {
        size_t o = (size_t)q * 256 + head * 32 + cg * 8;
        *(float4*)(attn + o)     = make_float4(acc[0], acc[1], acc[2], acc[3]);
        *(float4*)(attn + o + 4) = make_float4(acc[4], acc[5], acc[6], acc[7]);
    }
}

// ---------------------------------------------------------------------------
extern "C" void kernel_launch(void* const* d_in, const int* in_sizes, int n_in,
                              void* d_out, int out_size, void* d_ws, size_t ws_size,
                              hipStream_t stream)
{
    const float* query = (const float*)d_in[0];
    const float* refp  = (const float*)d_in[1];
    const float* toff  = (const float*)d_in[2];
    const float* inpf  = (const float*)d_in[3];
    const float* Wv  = (const float*)d_in[6];
    const float* bv  = (const float*)d_in[7];
    const float* Ws_ = (const float*)d_in[8];
    const float* bs_ = (const float*)d_in[9];
    const float* Wa  = (const float*)d_in[10];
    const float* ba  = (const float*)d_in[11];
    const float* Wts = (const float*)d_in[12];
    const float* bts = (const float*)d_in[13];
    const float* Wta = (const float*)d_in[14];
    const float* bta = (const float*)d_in[15];
    const float* Wo  = (const float*)d_in[16];
    const float* bo  = (const float*)d_in[17];
    float* out = (float*)d_out;

    // workspace layout (~39 MB)
    unsigned short* value_bf = (unsigned short*)d_ws;          // 8 x 8192 x 32 bf16 planes
    float* proj = (float*)(value_bf + (size_t)8 * 8192 * 32);  // 8160*768 f32
    float* attn = proj + (size_t)LEN * 768;                    // 8160*256 f32
    unsigned short* Whi = (unsigned short*)(attn + (size_t)LEN * 256);  // 1280*256
    unsigned short* Wlo = Whi + 1280 * 256;
    float* bcat = (float*)(Wlo + 1280 * 256);                  // 768

    prep_kernel<<<164, 256, 0, stream>>>(Ws_, bs_, Wa, ba, Wts, bts, Wta, bta,
                                         Wv, Wo, Whi, Wlo, bcat);
    // value(bf16 planes) = inpf @ Wv + bv (bx 0..3) ||
    // proj(f32) = query @ Bcat + bcat (bx 4..15); grid (16, 64) = 1024 blocks
    gemm_mfma_dual<<<dim3(16, 64), 256, 0, stream>>>(
        inpf, Whi, Wlo, bv, value_bf, 256, 1, 4,
        query, Whi + 256 * 256, Wlo + 256 * 256, bcat, proj, 768, 0);
    // deformable attention core -> attn (f32)
    sample_kernel<<<LEN, 256, 0, stream>>>(value_bf, proj, refp, toff, attn);
    // out(f32) = attn @ Wo + bo; grid (4, 64) = 256 blocks
    gemm_mfma_dual<<<dim3(4, 64), 256, 0, stream>>>(
        attn, Whi + 1024 * 256, Wlo + 1024 * 256, bo, out, 256, 0, 4,
        attn, Whi + 1024 * 256, Wlo + 1024 * 256, bo, out, 256, 0);
}